// Round 4
// baseline (229.746 us; speedup 1.0000x reference)
//
#include <hip/hip_runtime.h>

#define BB   4
#define SS   1024
#define DD   1024
#define HH   16
#define DHH  64
#define LN_EPS  (1e-3f)

typedef unsigned short u16;
typedef __attribute__((ext_vector_type(8))) short bf16x8;
typedef __attribute__((ext_vector_type(4))) float f32x4;

__device__ __forceinline__ u16 f2bf(float f) {
    union { float f; unsigned int u; } v; v.f = f;
    return (u16)((v.u + 0x7FFFu + ((v.u >> 16) & 1u)) >> 16);
}

// async global->LDS, 16B per lane; lane i lands at lds + i*16 (wave-uniform
// base, no per-lane scatter — swizzle is applied to the SOURCE address).
__device__ __forceinline__ void cp16(void* lds, const void* g) {
    __builtin_amdgcn_global_load_lds(
        (const __attribute__((address_space(1))) unsigned int*)g,
        (__attribute__((address_space(3))) unsigned int*)lds, 16, 0, 0);
}

// ---------------------------------------------------------------------------
// prep: z<3 -> fp32->bf16 convert of queries/keys/values into Abf[3][4096][1024]
//       z>=3 -> W[k][n] fp32 -> Wt[n][k] bf16 (transpose+convert)
// ---------------------------------------------------------------------------
__global__ __launch_bounds__(256) void prep(const float* __restrict__ q,
                                            const float* __restrict__ k,
                                            const float* __restrict__ v,
                                            const float* __restrict__ Wq,
                                            const float* __restrict__ Wk,
                                            const float* __restrict__ Wv,
                                            u16* __restrict__ Abf,
                                            u16* __restrict__ WtA) {
    __shared__ float Ts[64][65];
    const int z = blockIdx.z;
    const int tid = threadIdx.x;
    if (z < 3) {
        const float* src = (z == 0) ? q : (z == 1) ? k : v;
        u16* dst = Abf + (size_t)z * ((size_t)BB * SS * DD);
        const int N8 = BB * SS * DD / 8;
        for (int i = blockIdx.x * 256 + tid; i < N8; i += 256 * 256) {
            const float4 f0 = ((const float4*)src)[i * 2];
            const float4 f1 = ((const float4*)src)[i * 2 + 1];
            union { u16 u[8]; uint4 o; } t;
            t.u[0] = f2bf(f0.x); t.u[1] = f2bf(f0.y);
            t.u[2] = f2bf(f0.z); t.u[3] = f2bf(f0.w);
            t.u[4] = f2bf(f1.x); t.u[5] = f2bf(f1.y);
            t.u[6] = f2bf(f1.z); t.u[7] = f2bf(f1.w);
            ((uint4*)dst)[i] = t.o;
        }
    } else {
        const float* W = (z == 3) ? Wq : (z == 4) ? Wk : Wv;
        u16* Wt = WtA + (size_t)(z - 3) * DD * DD;
        const int k0 = (blockIdx.x >> 4) * 64, n0 = (blockIdx.x & 15) * 64;
        #pragma unroll
        for (int it = 0; it < 4; ++it) {
            const int idx = tid + it * 256;
            const int r = idx >> 4, c4 = (idx & 15) * 4;
            const float4 vv = *(const float4*)&W[(size_t)(k0 + r) * DD + n0 + c4];
            Ts[r][c4 + 0] = vv.x; Ts[r][c4 + 1] = vv.y;
            Ts[r][c4 + 2] = vv.z; Ts[r][c4 + 3] = vv.w;
        }
        __syncthreads();
        const int n = tid >> 2, kc = (tid & 3) * 16;
        #pragma unroll
        for (int p = 0; p < 8; ++p) {
            const unsigned int lo = f2bf(Ts[kc + p * 2 + 0][n]);
            const unsigned int hi = f2bf(Ts[kc + p * 2 + 1][n]);
            *(unsigned int*)&Wt[(size_t)(n0 + n) * DD + k0 + kc + p * 2] = lo | (hi << 16);
        }
    }
}

// ---------------------------------------------------------------------------
// Fused QKV projection GEMM, XCD-swizzled 1-D grid (768 blocks).
// xcd = bid&7 owns m-tiles 4*xcd..4*xcd+3 for all (n,z): per-XCD L2 working
// set = A 1MB + B 2MB < 4MB. z=0: Q*0.125 [b][h][s][dh]; z=1: K; z=2: V^T.
// ---------------------------------------------------------------------------
__global__ __launch_bounds__(256) void gemm_fused(const u16* __restrict__ Abf,
                                                  const u16* __restrict__ WtA,
                                                  u16* __restrict__ Qbf,
                                                  u16* __restrict__ Kbf,
                                                  u16* __restrict__ Vtb) {
    __shared__ u16 As[128 * 64];   // 16 KB, XOR-swizzled chunks
    __shared__ u16 Bs[128 * 64];
    const int bid = blockIdx.x;
    const int xcd = bid & 7;
    const int t   = bid >> 3;          // 0..95
    const int z   = t >> 5;            // 0..2
    const int rr  = t & 31;
    const int m0  = (xcd * 4 + (rr & 3)) * 128;
    const int n0  = (rr >> 2) * 128;

    const u16* A = Abf + (size_t)z * BB * SS * DD;
    const u16* B = WtA + (size_t)z * DD * DD;
    const int tid  = threadIdx.x;
    const int wave = tid >> 6, lane = tid & 63;
    const int ln = lane & 15, quad = lane >> 4;
    const int mw = (wave & 1) * 64, nw = (wave >> 1) * 64;

    f32x4 acc[4][4] = {};

    for (int k0 = 0; k0 < DD; k0 += 64) {
        __syncthreads();
        #pragma unroll
        for (int w = 0; w < 4; ++w) {
            const int s = w * 256 + wave * 64 + lane;
            const int r = s >> 3, csrc = (s & 7) ^ (r & 7);
            cp16(&As[(size_t)(w * 256 + wave * 64) * 8],
                 &A[(size_t)(m0 + r) * DD + k0 + csrc * 8]);
            cp16(&Bs[(size_t)(w * 256 + wave * 64) * 8],
                 &B[(size_t)(n0 + r) * DD + k0 + csrc * 8]);
        }
        __syncthreads();

        #pragma unroll
        for (int kk = 0; kk < 2; ++kk) {
            bf16x8 af[4], bfv[4];
            #pragma unroll
            for (int i = 0; i < 4; ++i) {
                const int r = mw + i * 16 + ln;
                af[i] = *(const bf16x8*)&As[((r << 3) + ((kk * 4 + quad) ^ (r & 7))) << 3];
            }
            #pragma unroll
            for (int j = 0; j < 4; ++j) {
                const int r = nw + j * 16 + ln;
                bfv[j] = *(const bf16x8*)&Bs[((r << 3) + ((kk * 4 + quad) ^ (r & 7))) << 3];
            }
            #pragma unroll
            for (int i = 0; i < 4; ++i)
                #pragma unroll
                for (int j = 0; j < 4; ++j)
                    acc[i][j] = __builtin_amdgcn_mfma_f32_16x16x32_bf16(af[i], bfv[j], acc[i][j], 0, 0, 0);
        }
    }

    if (z < 2) {
        u16* C = (z == 0) ? Qbf : Kbf;
        const float scale = (z == 0) ? 0.125f : 1.0f;   // fold 1/sqrt(64) into Q
        #pragma unroll
        for (int i = 0; i < 4; ++i) {
            const int mbase = m0 + mw + i * 16 + quad * 4;
            const int bb = mbase >> 10, sb = mbase & 1023;
            #pragma unroll
            for (int j = 0; j < 4; ++j) {
                const int n = n0 + nw + j * 16 + ln;
                const int hh = n >> 6, dh = n & 63;
                #pragma unroll
                for (int r = 0; r < 4; ++r)
                    C[(((size_t)bb * HH + hh) * SS + sb + r) * DHH + dh] =
                        f2bf(acc[i][j][r] * scale);
            }
        }
    } else {
        #pragma unroll
        for (int i = 0; i < 4; ++i) {
            const int mbase = m0 + mw + i * 16 + quad * 4;
            const int bb = mbase >> 10, sb = mbase & 1023;
            #pragma unroll
            for (int j = 0; j < 4; ++j) {
                const int n = n0 + nw + j * 16 + ln;
                const int hh = n >> 6, dh = n & 63;
                uint2 pk;
                pk.x = (unsigned int)f2bf(acc[i][j][0]) | ((unsigned int)f2bf(acc[i][j][1]) << 16);
                pk.y = (unsigned int)f2bf(acc[i][j][2]) | ((unsigned int)f2bf(acc[i][j][3]) << 16);
                *(uint2*)&Vtb[(((size_t)bb * HH + hh) * DHH + dh) * SS + sb] = pk;
            }
        }
    }
}

// ---------------------------------------------------------------------------
// Flash attention, MFMA, no-max softmax. 128 keys staged per barrier pair
// (2x MFMA per drain), processed as two 64-key halves. Ps overlays the dead
// Q-staging buffer (wave-private rows -> no extra barriers). LDS 41.5KB.
// ---------------------------------------------------------------------------
__global__ __launch_bounds__(256) void attn_mfma(const u16* __restrict__ Qg,
                                                 const u16* __restrict__ Kg,
                                                 const u16* __restrict__ Vtg,
                                                 const int* __restrict__ qmask,
                                                 const int* __restrict__ kmask,
                                                 float* __restrict__ O) {
    __shared__ u16 QPs[64 * 68];   // Q stage (first 8KB, swizzled) then Ps pitch-68
    __shared__ u16 Ks[128 * 64];   // [key 128][dh 64] swizzled, 16 KB
    __shared__ u16 Vs[64 * 128];   // [dh 64][key 128] swizzled, 16 KB

    const int bi = blockIdx.x;
    const int qt = bi & 15;
    const int h  = (bi >> 4) & 15;
    const int b  = bi >> 8;
    const int q0 = qt * 64;
    const int tid  = threadIdx.x;
    const int wave = tid >> 6, lane = tid & 63;
    const int ln = lane & 15, quad = lane >> 4;
    const size_t bh = (size_t)b * HH + h;

    // stage Q (swizzled 8-chunk rows)
    #pragma unroll
    for (int w = 0; w < 2; ++w) {
        const int s = w * 256 + wave * 64 + lane;
        const int r = s >> 3, csrc = (s & 7) ^ (r & 7);
        cp16(&QPs[(size_t)(w * 256 + wave * 64) * 8],
             &Qg[(bh * SS + q0 + r) * DHH + csrc * 8]);
    }
    __syncthreads();

    bf16x8 qf[2];
    #pragma unroll
    for (int kk = 0; kk < 2; ++kk) {
        const int r = wave * 16 + ln;
        qf[kk] = *(const bf16x8*)&QPs[((r << 3) + ((kk * 4 + quad) ^ (r & 7))) << 3];
    }

    f32x4 o[4] = {};
    float lsum[4] = {0.f, 0.f, 0.f, 0.f};
    const f32x4 zero = {0.f, 0.f, 0.f, 0.f};

    for (int kt = 0; kt < SS / 128; ++kt) {
        __syncthreads();   // prior tile's reads done before restage
        #pragma unroll
        for (int w = 0; w < 4; ++w) {
            const int s = w * 256 + wave * 64 + lane;
            const int rk = s >> 3, ck = (s & 7) ^ (rk & 7);
            cp16(&Ks[(size_t)(w * 256 + wave * 64) * 8],
                 &Kg[(bh * SS + kt * 128 + rk) * DHH + ck * 8]);
        }
        #pragma unroll
        for (int w = 0; w < 4; ++w) {
            const int s = w * 256 + wave * 64 + lane;
            const int rv = s >> 4, cv = (s & 15) ^ (rv & 15);
            cp16(&Vs[(size_t)(w * 256 + wave * 64) * 8],
                 &Vtg[(bh * DHH + rv) * SS + kt * 128 + cv * 8]);
        }
        __syncthreads();

        #pragma unroll
        for (int hh = 0; hh < 2; ++hh) {
            // S = Q @ K^T (Q pre-scaled); p = mask * exp(s); spill to Ps
            #pragma unroll
            for (int nt = 0; nt < 4; ++nt) {
                const int krow = hh * 64 + nt * 16 + ln;
                const bf16x8 k0f = *(const bf16x8*)&Ks[((krow << 3) + ((0 + quad) ^ (krow & 7))) << 3];
                const bf16x8 k1f = *(const bf16x8*)&Ks[((krow << 3) + ((4 + quad) ^ (krow & 7))) << 3];
                f32x4 sacc = __builtin_amdgcn_mfma_f32_16x16x32_bf16(qf[0], k0f, zero, 0, 0, 0);
                sacc = __builtin_amdgcn_mfma_f32_16x16x32_bf16(qf[1], k1f, sacc, 0, 0, 0);
                const int km = kmask[b * SS + kt * 128 + hh * 64 + nt * 16 + ln];
                #pragma unroll
                for (int r = 0; r < 4; ++r) {
                    const float p = km ? __expf(sacc[r]) : 0.0f;
                    lsum[r] += p;
                    QPs[(wave * 16 + quad * 4 + r) * 68 + nt * 16 + ln] = f2bf(p);
                }
            }
            // O += P @ V   (Ps rows are wave-private; same-wave lgkm ordering)
            #pragma unroll
            for (int kk2 = 0; kk2 < 2; ++kk2) {
                const bf16x8 pf = *(const bf16x8*)&QPs[(wave * 16 + ln) * 68 + kk2 * 32 + quad * 8];
                #pragma unroll
                for (int nt2 = 0; nt2 < 4; ++nt2) {
                    const int vrow = nt2 * 16 + ln;
                    const int vch  = hh * 8 + kk2 * 4 + quad;
                    const bf16x8 vf = *(const bf16x8*)&Vs[((vrow << 4) + (vch ^ (vrow & 15))) << 3];
                    o[nt2] = __builtin_amdgcn_mfma_f32_16x16x32_bf16(pf, vf, o[nt2], 0, 0, 0);
                }
            }
        }
    }

    // epilogue: one cross-lane l-reduction, normalize, query mask, store
    #pragma unroll
    for (int r = 0; r < 4; ++r) {
        #pragma unroll
        for (int off = 1; off < 16; off <<= 1)
            lsum[r] += __shfl_xor(lsum[r], off);
        const int q = q0 + wave * 16 + quad * 4 + r;
        const float scale = (float)qmask[b * SS + q] / lsum[r];
        #pragma unroll
        for (int nt2 = 0; nt2 < 4; ++nt2)
            O[((size_t)b * SS + q) * DD + h * DHH + nt2 * 16 + ln] = o[nt2][r] * scale;
    }
}

// ---------------------------------------------------------------------------
// residual + LayerNorm over D=1024. One block (256 thr) per (b,s) row.
// ---------------------------------------------------------------------------
__global__ __launch_bounds__(256) void ln_kernel(const float* __restrict__ Qin,
                                                 const float* __restrict__ attn,
                                                 const float* __restrict__ gamma,
                                                 const float* __restrict__ beta,
                                                 float* __restrict__ out) {
    const int row = blockIdx.x;
    const int tid = threadIdx.x;
    const int wid = tid >> 6, lane = tid & 63;
    __shared__ float sred[4];

    const float4 qv = ((const float4*)Qin)[(size_t)row * 256 + tid];
    const float4 av = ((const float4*)attn)[(size_t)row * 256 + tid];
    float4 v;
    v.x = qv.x + av.x; v.y = qv.y + av.y;
    v.z = qv.z + av.z; v.w = qv.w + av.w;

    float sum = v.x + v.y + v.z + v.w;
    #pragma unroll
    for (int off = 32; off; off >>= 1) sum += __shfl_down(sum, off);
    if (lane == 0) sred[wid] = sum;
    __syncthreads();
    const float mean = (sred[0] + sred[1] + sred[2] + sred[3]) * (1.0f / DD);
    __syncthreads();

    const float dx = v.x - mean, dy = v.y - mean, dz = v.z - mean, dw = v.w - mean;
    float vs = dx * dx + dy * dy + dz * dz + dw * dw;
    #pragma unroll
    for (int off = 32; off; off >>= 1) vs += __shfl_down(vs, off);
    if (lane == 0) sred[wid] = vs;
    __syncthreads();
    const float var = (sred[0] + sred[1] + sred[2] + sred[3]) * (1.0f / DD);
    const float inv = rsqrtf(var + LN_EPS);

    const float4 g = ((const float4*)gamma)[tid];
    const float4 bt = ((const float4*)beta)[tid];
    float4 ov;
    ov.x = g.x * dx * inv + bt.x; ov.y = g.y * dy * inv + bt.y;
    ov.z = g.z * dz * inv + bt.z; ov.w = g.w * dw * inv + bt.w;
    ((float4*)out)[(size_t)row * 256 + tid] = ov;
}

// ---------------------------------------------------------------------------
extern "C" void kernel_launch(void* const* d_in, const int* in_sizes, int n_in,
                              void* d_out, int out_size, void* d_ws, size_t ws_size,
                              hipStream_t stream) {
    const float* queries = (const float*)d_in[0];
    const float* keys    = (const float*)d_in[1];
    const float* values  = (const float*)d_in[2];
    const int*   qmask   = (const int*)d_in[3];
    const int*   kmask   = (const int*)d_in[4];
    const float* Wq      = (const float*)d_in[5];
    const float* Wk      = (const float*)d_in[6];
    const float* Wv      = (const float*)d_in[7];
    const float* gamma   = (const float*)d_in[8];
    const float* beta    = (const float*)d_in[9];
    float* out = (float*)d_out;

    const size_t NTOK = (size_t)BB * SS;          // 4096
    // layout (54 MB): Abf[3] 24MB (Ob 16MB ALIASES it — gemm finishes reading
    // Abf before attn writes Ob; stream-ordered) | Qbf 8 | Kbf 8 | Vtb 8 | Wt 6
    u16* Abf = (u16*)d_ws;
    float* Ob = (float*)d_ws;
    u16* Qbf = Abf + 3 * NTOK * DD;
    u16* Kbf = Qbf + NTOK * DD;
    u16* Vtb = Kbf + NTOK * DD;
    u16* WtA = Vtb + NTOK * DD;

    prep<<<dim3(256, 1, 6), 256, 0, stream>>>(queries, keys, values, Wq, Wk, Wv, Abf, WtA);

    gemm_fused<<<768, 256, 0, stream>>>(Abf, WtA, Qbf, Kbf, Vtb);

    attn_mfma<<<BB * HH * (SS / 64), 256, 0, stream>>>(Qbf, Kbf, Vtb, qmask, kmask, Ob);

    ln_kernel<<<BB * SS, 256, 0, stream>>>(queries, Ob, gamma, beta, out);
}

// Round 5
// 204.923 us; speedup vs baseline: 1.1211x; 1.1211x over previous
//
#include <hip/hip_runtime.h>

#define BB   4
#define SS   1024
#define DD   1024
#define HH   16
#define DHH  64
#define LN_EPS  (1e-3f)

typedef unsigned short u16;
typedef __attribute__((ext_vector_type(8))) short bf16x8;
typedef __attribute__((ext_vector_type(4))) float f32x4;

__device__ __forceinline__ u16 f2bf(float f) {
    union { float f; unsigned int u; } v; v.f = f;
    return (u16)((v.u + 0x7FFFu + ((v.u >> 16) & 1u)) >> 16);
}

// async global->LDS, 16B per lane; lane i lands at lds + i*16 (wave-uniform
// base, no per-lane scatter — swizzle is applied to the SOURCE address).
__device__ __forceinline__ void cp16(void* lds, const void* g) {
    __builtin_amdgcn_global_load_lds(
        (const __attribute__((address_space(1))) unsigned int*)g,
        (__attribute__((address_space(3))) unsigned int*)lds, 16, 0, 0);
}

// ---------------------------------------------------------------------------
// prep: z<3 -> fp32->bf16 convert of queries/keys/values into Abf[3][4096][1024]
//       z>=3 -> W[k][n] fp32 -> Wt[n][k] bf16 (transpose+convert)
// ---------------------------------------------------------------------------
__global__ __launch_bounds__(256) void prep(const float* __restrict__ q,
                                            const float* __restrict__ k,
                                            const float* __restrict__ v,
                                            const float* __restrict__ Wq,
                                            const float* __restrict__ Wk,
                                            const float* __restrict__ Wv,
                                            u16* __restrict__ Abf,
                                            u16* __restrict__ WtA) {
    __shared__ float Ts[64][65];
    const int z = blockIdx.z;
    const int tid = threadIdx.x;
    if (z < 3) {
        const float* src = (z == 0) ? q : (z == 1) ? k : v;
        u16* dst = Abf + (size_t)z * ((size_t)BB * SS * DD);
        const int N8 = BB * SS * DD / 8;
        for (int i = blockIdx.x * 256 + tid; i < N8; i += 256 * 256) {
            const float4 f0 = ((const float4*)src)[i * 2];
            const float4 f1 = ((const float4*)src)[i * 2 + 1];
            union { u16 u[8]; uint4 o; } t;
            t.u[0] = f2bf(f0.x); t.u[1] = f2bf(f0.y);
            t.u[2] = f2bf(f0.z); t.u[3] = f2bf(f0.w);
            t.u[4] = f2bf(f1.x); t.u[5] = f2bf(f1.y);
            t.u[6] = f2bf(f1.z); t.u[7] = f2bf(f1.w);
            ((uint4*)dst)[i] = t.o;
        }
    } else {
        const float* W = (z == 3) ? Wq : (z == 4) ? Wk : Wv;
        u16* Wt = WtA + (size_t)(z - 3) * DD * DD;
        const int k0 = (blockIdx.x >> 4) * 64, n0 = (blockIdx.x & 15) * 64;
        #pragma unroll
        for (int it = 0; it < 4; ++it) {
            const int idx = tid + it * 256;
            const int r = idx >> 4, c4 = (idx & 15) * 4;
            const float4 vv = *(const float4*)&W[(size_t)(k0 + r) * DD + n0 + c4];
            Ts[r][c4 + 0] = vv.x; Ts[r][c4 + 1] = vv.y;
            Ts[r][c4 + 2] = vv.z; Ts[r][c4 + 3] = vv.w;
        }
        __syncthreads();
        const int n = tid >> 2, kc = (tid & 3) * 16;
        #pragma unroll
        for (int p = 0; p < 8; ++p) {
            const unsigned int lo = f2bf(Ts[kc + p * 2 + 0][n]);
            const unsigned int hi = f2bf(Ts[kc + p * 2 + 1][n]);
            *(unsigned int*)&Wt[(size_t)(n0 + n) * DD + k0 + kc + p * 2] = lo | (hi << 16);
        }
    }
}

// ---------------------------------------------------------------------------
// Fused QKV projection GEMM, XCD-swizzled 1-D grid (768 blocks).
// xcd = bid&7 owns m-tiles 4*xcd..4*xcd+3 for all (n,z): per-XCD L2 working
// set = A 1MB + B 2MB < 4MB. z=0: Q*0.125 [b][h][s][dh]; z=1: K; z=2: V^T.
// ---------------------------------------------------------------------------
__global__ __launch_bounds__(256) void gemm_fused(const u16* __restrict__ Abf,
                                                  const u16* __restrict__ WtA,
                                                  u16* __restrict__ Qbf,
                                                  u16* __restrict__ Kbf,
                                                  u16* __restrict__ Vtb) {
    __shared__ u16 As[128 * 64];   // 16 KB, XOR-swizzled chunks
    __shared__ u16 Bs[128 * 64];
    const int bid = blockIdx.x;
    const int xcd = bid & 7;
    const int t   = bid >> 3;          // 0..95
    const int z   = t >> 5;            // 0..2
    const int rr  = t & 31;
    const int m0  = (xcd * 4 + (rr & 3)) * 128;
    const int n0  = (rr >> 2) * 128;

    const u16* A = Abf + (size_t)z * BB * SS * DD;
    const u16* B = WtA + (size_t)z * DD * DD;
    const int tid  = threadIdx.x;
    const int wave = tid >> 6, lane = tid & 63;
    const int ln = lane & 15, quad = lane >> 4;
    const int mw = (wave & 1) * 64, nw = (wave >> 1) * 64;

    f32x4 acc[4][4] = {};

    for (int k0 = 0; k0 < DD; k0 += 64) {
        __syncthreads();
        #pragma unroll
        for (int w = 0; w < 4; ++w) {
            const int s = w * 256 + wave * 64 + lane;
            const int r = s >> 3, csrc = (s & 7) ^ (r & 7);
            cp16(&As[(size_t)(w * 256 + wave * 64) * 8],
                 &A[(size_t)(m0 + r) * DD + k0 + csrc * 8]);
            cp16(&Bs[(size_t)(w * 256 + wave * 64) * 8],
                 &B[(size_t)(n0 + r) * DD + k0 + csrc * 8]);
        }
        __syncthreads();

        #pragma unroll
        for (int kk = 0; kk < 2; ++kk) {
            bf16x8 af[4], bfv[4];
            #pragma unroll
            for (int i = 0; i < 4; ++i) {
                const int r = mw + i * 16 + ln;
                af[i] = *(const bf16x8*)&As[((r << 3) + ((kk * 4 + quad) ^ (r & 7))) << 3];
            }
            #pragma unroll
            for (int j = 0; j < 4; ++j) {
                const int r = nw + j * 16 + ln;
                bfv[j] = *(const bf16x8*)&Bs[((r << 3) + ((kk * 4 + quad) ^ (r & 7))) << 3];
            }
            #pragma unroll
            for (int i = 0; i < 4; ++i)
                #pragma unroll
                for (int j = 0; j < 4; ++j)
                    acc[i][j] = __builtin_amdgcn_mfma_f32_16x16x32_bf16(af[i], bfv[j], acc[i][j], 0, 0, 0);
        }
    }

    if (z < 2) {
        u16* C = (z == 0) ? Qbf : Kbf;
        const float scale = (z == 0) ? 0.125f : 1.0f;   // fold 1/sqrt(64) into Q
        #pragma unroll
        for (int i = 0; i < 4; ++i) {
            const int mbase = m0 + mw + i * 16 + quad * 4;
            const int bb = mbase >> 10, sb = mbase & 1023;
            #pragma unroll
            for (int j = 0; j < 4; ++j) {
                const int n = n0 + nw + j * 16 + ln;
                const int hh = n >> 6, dh = n & 63;
                #pragma unroll
                for (int r = 0; r < 4; ++r)
                    C[(((size_t)bb * HH + hh) * SS + sb + r) * DHH + dh] =
                        f2bf(acc[i][j][r] * scale);
            }
        }
    } else {
        #pragma unroll
        for (int i = 0; i < 4; ++i) {
            const int mbase = m0 + mw + i * 16 + quad * 4;
            const int bb = mbase >> 10, sb = mbase & 1023;
            #pragma unroll
            for (int j = 0; j < 4; ++j) {
                const int n = n0 + nw + j * 16 + ln;
                const int hh = n >> 6, dh = n & 63;
                uint2 pk;
                pk.x = (unsigned int)f2bf(acc[i][j][0]) | ((unsigned int)f2bf(acc[i][j][1]) << 16);
                pk.y = (unsigned int)f2bf(acc[i][j][2]) | ((unsigned int)f2bf(acc[i][j][3]) << 16);
                *(uint2*)&Vtb[(((size_t)bb * HH + hh) * DHH + dh) * SS + sb] = pk;
            }
        }
    }
}

// ---------------------------------------------------------------------------
// Flash attention, MFMA, no-max softmax. 64-key tiles (LDS 24.5 KB -> full
// 4 blocks/CU co-residency). Ps overlays the dead Q-staging buffer. XCD
// decode: xcd=bid&7 selects (b,h) residue -> each XCD reuses only 8 K/V
// pairs (2 MB, fits per-XCD L2).
// ---------------------------------------------------------------------------
__global__ __launch_bounds__(256) void attn_mfma(const u16* __restrict__ Qg,
                                                 const u16* __restrict__ Kg,
                                                 const u16* __restrict__ Vtg,
                                                 const int* __restrict__ qmask,
                                                 const int* __restrict__ kmask,
                                                 float* __restrict__ O) {
    __shared__ u16 QPs[64 * 68];   // Q stage (first 8KB, swizzled), then Ps pitch-68
    __shared__ u16 Ks[64 * 64];    // [key][dh] swizzled chunks, 8 KB
    __shared__ u16 Vs[64 * 64];    // [dh][key] swizzled chunks, 8 KB

    const int bid  = blockIdx.x;
    const int xcd  = bid & 7;
    const int rest = bid >> 3;           // 0..127
    const int bh   = (rest & 7) * 8 + xcd;   // 0..63
    const int qt   = rest >> 3;          // 0..15
    const int b    = bh >> 4, h = bh & 15;
    const int q0   = qt * 64;
    const int tid  = threadIdx.x;
    const int wave = tid >> 6, lane = tid & 63;
    const int ln = lane & 15, quad = lane >> 4;
    const size_t bhs = (size_t)b * HH + h;

    // stage Q (swizzled 8-chunk rows)
    #pragma unroll
    for (int w = 0; w < 2; ++w) {
        const int s = w * 256 + wave * 64 + lane;
        const int r = s >> 3, csrc = (s & 7) ^ (r & 7);
        cp16(&QPs[(size_t)(w * 256 + wave * 64) * 8],
             &Qg[(bhs * SS + q0 + r) * DHH + csrc * 8]);
    }
    __syncthreads();

    bf16x8 qf[2];
    #pragma unroll
    for (int kk = 0; kk < 2; ++kk) {
        const int r = wave * 16 + ln;
        qf[kk] = *(const bf16x8*)&QPs[((r << 3) + ((kk * 4 + quad) ^ (r & 7))) << 3];
    }

    f32x4 o[4] = {};
    float lsum[4] = {0.f, 0.f, 0.f, 0.f};
    const f32x4 zero = {0.f, 0.f, 0.f, 0.f};

    for (int kt = 0; kt < SS / 64; ++kt) {
        __syncthreads();   // prior tile's reads done before restage
        #pragma unroll
        for (int w = 0; w < 2; ++w) {
            const int s = w * 256 + wave * 64 + lane;
            const int r = s >> 3, csrc = (s & 7) ^ (r & 7);
            cp16(&Ks[(size_t)(w * 256 + wave * 64) * 8],
                 &Kg[(bhs * SS + kt * 64 + r) * DHH + csrc * 8]);
            cp16(&Vs[(size_t)(w * 256 + wave * 64) * 8],
                 &Vtg[(bhs * DHH + r) * SS + kt * 64 + csrc * 8]);
        }
        __syncthreads();

        // S = Q @ K^T (Q pre-scaled); p = mask * exp(s); spill to Ps
        #pragma unroll
        for (int nt = 0; nt < 4; ++nt) {
            const int krow = nt * 16 + ln;
            const bf16x8 k0f = *(const bf16x8*)&Ks[((krow << 3) + ((0 + quad) ^ (krow & 7))) << 3];
            const bf16x8 k1f = *(const bf16x8*)&Ks[((krow << 3) + ((4 + quad) ^ (krow & 7))) << 3];
            f32x4 sacc = __builtin_amdgcn_mfma_f32_16x16x32_bf16(qf[0], k0f, zero, 0, 0, 0);
            sacc = __builtin_amdgcn_mfma_f32_16x16x32_bf16(qf[1], k1f, sacc, 0, 0, 0);
            const int km = kmask[b * SS + kt * 64 + krow];
            #pragma unroll
            for (int r = 0; r < 4; ++r) {
                const float p = km ? __expf(sacc[r]) : 0.0f;
                lsum[r] += p;
                QPs[(wave * 16 + quad * 4 + r) * 68 + nt * 16 + ln] = f2bf(p);
            }
        }
        // Ps rows are wave-private; same-wave lgkm ordering covers the RAW.

        // O += P @ V
        #pragma unroll
        for (int kk2 = 0; kk2 < 2; ++kk2) {
            const bf16x8 pf = *(const bf16x8*)&QPs[(wave * 16 + ln) * 68 + kk2 * 32 + quad * 8];
            #pragma unroll
            for (int nt2 = 0; nt2 < 4; ++nt2) {
                const int vrow = nt2 * 16 + ln;
                const bf16x8 vf = *(const bf16x8*)&Vs[((vrow << 3) + ((kk2 * 4 + quad) ^ (vrow & 7))) << 3];
                o[nt2] = __builtin_amdgcn_mfma_f32_16x16x32_bf16(pf, vf, o[nt2], 0, 0, 0);
            }
        }
    }

    // epilogue: one cross-lane l-reduction, normalize, query mask, store
    #pragma unroll
    for (int r = 0; r < 4; ++r) {
        #pragma unroll
        for (int off = 1; off < 16; off <<= 1)
            lsum[r] += __shfl_xor(lsum[r], off);
        const int q = q0 + wave * 16 + quad * 4 + r;
        const float scale = (float)qmask[b * SS + q] / lsum[r];
        #pragma unroll
        for (int nt2 = 0; nt2 < 4; ++nt2)
            O[((size_t)b * SS + q) * DD + h * DHH + nt2 * 16 + ln] = o[nt2][r] * scale;
    }
}

// ---------------------------------------------------------------------------
// residual + LayerNorm over D=1024. One block (256 thr) per (b,s) row.
// ---------------------------------------------------------------------------
__global__ __launch_bounds__(256) void ln_kernel(const float* __restrict__ Qin,
                                                 const float* __restrict__ attn,
                                                 const float* __restrict__ gamma,
                                                 const float* __restrict__ beta,
                                                 float* __restrict__ out) {
    const int row = blockIdx.x;
    const int tid = threadIdx.x;
    const int wid = tid >> 6, lane = tid & 63;
    __shared__ float sred[4];

    const float4 qv = ((const float4*)Qin)[(size_t)row * 256 + tid];
    const float4 av = ((const float4*)attn)[(size_t)row * 256 + tid];
    float4 v;
    v.x = qv.x + av.x; v.y = qv.y + av.y;
    v.z = qv.z + av.z; v.w = qv.w + av.w;

    float sum = v.x + v.y + v.z + v.w;
    #pragma unroll
    for (int off = 32; off; off >>= 1) sum += __shfl_down(sum, off);
    if (lane == 0) sred[wid] = sum;
    __syncthreads();
    const float mean = (sred[0] + sred[1] + sred[2] + sred[3]) * (1.0f / DD);
    __syncthreads();

    const float dx = v.x - mean, dy = v.y - mean, dz = v.z - mean, dw = v.w - mean;
    float vs = dx * dx + dy * dy + dz * dz + dw * dw;
    #pragma unroll
    for (int off = 32; off; off >>= 1) vs += __shfl_down(vs, off);
    if (lane == 0) sred[wid] = vs;
    __syncthreads();
    const float var = (sred[0] + sred[1] + sred[2] + sred[3]) * (1.0f / DD);
    const float inv = rsqrtf(var + LN_EPS);

    const float4 g = ((const float4*)gamma)[tid];
    const float4 bt = ((const float4*)beta)[tid];
    float4 ov;
    ov.x = g.x * dx * inv + bt.x; ov.y = g.y * dy * inv + bt.y;
    ov.z = g.z * dz * inv + bt.z; ov.w = g.w * dw * inv + bt.w;
    ((float4*)out)[(size_t)row * 256 + tid] = ov;
}

// ---------------------------------------------------------------------------
extern "C" void kernel_launch(void* const* d_in, const int* in_sizes, int n_in,
                              void* d_out, int out_size, void* d_ws, size_t ws_size,
                              hipStream_t stream) {
    const float* queries = (const float*)d_in[0];
    const float* keys    = (const float*)d_in[1];
    const float* values  = (const float*)d_in[2];
    const int*   qmask   = (const int*)d_in[3];
    const int*   kmask   = (const int*)d_in[4];
    const float* Wq      = (const float*)d_in[5];
    const float* Wk      = (const float*)d_in[6];
    const float* Wv      = (const float*)d_in[7];
    const float* gamma   = (const float*)d_in[8];
    const float* beta    = (const float*)d_in[9];
    float* out = (float*)d_out;

    const size_t NTOK = (size_t)BB * SS;          // 4096
    // layout (54 MB): Abf[3] 24MB (Ob 16MB ALIASES it — gemm finishes reading
    // Abf before attn writes Ob; stream-ordered) | Qbf 8 | Kbf 8 | Vtb 8 | Wt 6
    u16* Abf = (u16*)d_ws;
    float* Ob = (float*)d_ws;
    u16* Qbf = Abf + 3 * NTOK * DD;
    u16* Kbf = Qbf + NTOK * DD;
    u16* Vtb = Kbf + NTOK * DD;
    u16* WtA = Vtb + NTOK * DD;

    prep<<<dim3(256, 1, 6), 256, 0, stream>>>(queries, keys, values, Wq, Wk, Wv, Abf, WtA);

    gemm_fused<<<768, 256, 0, stream>>>(Abf, WtA, Qbf, Kbf, Vtb);

    attn_mfma<<<BB * HH * (SS / 64), 256, 0, stream>>>(Qbf, Kbf, Vtb, qmask, kmask, Ob);

    ln_kernel<<<BB * SS, 256, 0, stream>>>(queries, Ob, gamma, beta, out);
}